// Round 6
// baseline (214.493 us; speedup 1.0000x reference)
//
#include <hip/hip_runtime.h>
#include <hip/hip_bf16.h>

#define L_SEQ 4096
#define C_DIM 256
#define QKV_N 768

typedef short bf16x8 __attribute__((ext_vector_type(8)));
typedef float f32x4  __attribute__((ext_vector_type(4)));
typedef float f32x16 __attribute__((ext_vector_type(16)));

#if defined(__has_builtin)
#  if __has_builtin(__builtin_amdgcn_permlane32_swap)
#    define HAVE_PLSWAP 1
#  endif
#endif

__device__ inline short f2bf(float f){ union{__hip_bfloat16 h; short s;}u; u.h=__float2bfloat16(f); return u.s; }
__device__ inline float bf2f(short s){ union{unsigned u; float f;}x; x.u=((unsigned)(unsigned short)s)<<16; return x.f; }

__device__ inline unsigned cvtpk(float lo, float hi){
  unsigned r;
  asm("v_cvt_pk_bf16_f32 %0, %1, %2" : "=v"(r) : "v"(lo), "v"(hi));
  return r;
}

__device__ inline void plswap(unsigned &a, unsigned &b){
#ifdef HAVE_PLSWAP
  auto r = __builtin_amdgcn_permlane32_swap(a, b, false, false);
  a = r[0]; b = r[1];
#else
  unsigned ax = __shfl_xor((int)a, 32);
  unsigned bx = __shfl_xor((int)b, 32);
  bool hi = (threadIdx.x & 32) != 0;
  unsigned na = hi ? bx : a;
  unsigned nb = hi ? b : ax;
  a = na; b = nb;
#endif
}

// ---------------------------------------------------------------------------
// tables: pe_t[c][l] bf16 (blocks 0..4095)  |  wT[j][k] bf16 (blocks 4096..4863)
// (byte-identical to round-5 green version)
// ---------------------------------------------------------------------------
__global__ __launch_bounds__(256) void tables_kernel(
    const float* __restrict__ W, short* __restrict__ pe_t, short* __restrict__ wT){
  int bid = blockIdx.x;
  if (bid < 4096){
    int idx = bid*256 + threadIdx.x;           // c*4096 + l
    int c = idx >> 12, l = idx & 4095;
    int c2 = c & ~1;
    float inv = __expf(-(float)c2 * (9.210340371976184f/256.0f));   // 10000^(-c2/256)
    float rev = (float)l * inv * 0.15915494309189535f;              // revolutions
    float fr = rev - floorf(rev);
    float v = (c & 1) ? __builtin_amdgcn_cosf(fr) : __builtin_amdgcn_sinf(fr);
    pe_t[idx] = f2bf(v);
  } else {
    int idx = (bid - 4096)*256 + threadIdx.x;  // jj*256 + k
    int jj = idx >> 8, k = idx & 255;
    wT[idx] = f2bf(W[k*QKV_N + jj]);
  }
}

// ---------------------------------------------------------------------------
// qkv GEMM (byte-identical to round-5 green version): BM=64, BN=192, 4 waves,
// A staged once, B dbuf. 64.5KB LDS -> 2 blocks/CU, grid (256,4).
// ---------------------------------------------------------------------------
__global__ __launch_bounds__(256) void qkv_gemm(
    const float* __restrict__ x, const short* __restrict__ pe_t, const short* __restrict__ wT,
    short* __restrict__ qw, short* __restrict__ kw, short* __restrict__ vtw){
  __shared__ __align__(16) short A_lds[64][264];     // [l][c] pad (528B rows) 33.8KB
  __shared__ __align__(16) short B_lds[2][192][40];  // [buf][j][k] pad (80B rows) 30.7KB
  int m0 = blockIdx.x * 64;
  int n = m0 >> 12, l0 = m0 & 4095;
  int j0 = blockIdx.y * 192;
  int tid = threadIdx.x;

  {  // ---- stage A = bf16(x^T + pe), 64 x 256, once; thread = one c-column ----
    int c = tid;
    const float* xp = x + ((size_t)n*C_DIM + c)*L_SEQ + l0;
    const short* pp = pe_t + (size_t)c*L_SEQ + l0;
    float xv[64];
#pragma unroll
    for (int q = 0; q < 16; ++q) *(float4*)&xv[q*4] = ((const float4*)xp)[q];
    short pv[64];
#pragma unroll
    for (int q = 0; q < 8; ++q) *(bf16x8*)&pv[q*8] = ((const bf16x8*)pp)[q];
#pragma unroll
    for (int i = 0; i < 64; ++i) A_lds[i][c] = f2bf(xv[i] + bf2f(pv[i]));
  }
  {  // ---- stage B slice 0 (192 x 32 shorts = 768 x 16B chunks, 256 thr x 3) ----
#pragma unroll
    for (int s = 0; s < 3; ++s){
      int chunk = tid + s*256;
      int j = chunk >> 2, kc = chunk & 3;
      *(bf16x8*)&B_lds[0][j][kc*8] = *(const bf16x8*)(wT + (size_t)(j0 + j)*256 + kc*8);
    }
  }
  __syncthreads();

  int wv = tid >> 6, lane = tid & 63, r = lane & 15, g = lane >> 4;
  f32x4 acc[4][3] = {};

  for (int ks = 0; ks < 8; ++ks){
    int buf = ks & 1;
    bf16x8 pre[3];
    if (ks < 7){                                 // issue next-slice loads early
#pragma unroll
      for (int s = 0; s < 3; ++s){
        int chunk = tid + s*256;
        int j = chunk >> 2, kc = chunk & 3;
        pre[s] = *(const bf16x8*)(wT + (size_t)(j0 + j)*256 + (ks+1)*32 + kc*8);
      }
    }
    bf16x8 a[4];
#pragma unroll
    for (int mf = 0; mf < 4; ++mf)
      a[mf] = *(const bf16x8*)&A_lds[mf*16 + r][ks*32 + g*8];
#pragma unroll
    for (int t = 0; t < 3; ++t){
      bf16x8 b = *(const bf16x8*)&B_lds[buf][wv*48 + t*16 + r][g*8];
#pragma unroll
      for (int mf = 0; mf < 4; ++mf)
        acc[mf][t] = __builtin_amdgcn_mfma_f32_16x16x32_bf16(a[mf], b, acc[mf][t], 0,0,0);
    }
    if (ks < 7){                                 // write NEXT slice to other buffer
#pragma unroll
      for (int s = 0; s < 3; ++s){
        int chunk = tid + s*256;
        int j = chunk >> 2, kc = chunk & 3;
        *(bf16x8*)&B_lds[buf^1][j][kc*8] = pre[s];
      }
    }
    __syncthreads();
  }

  const float QSCALE = 0.17677669529663687f * 1.4426950408889634f;  // 1/sqrt(32) * log2e
#pragma unroll
  for (int mf = 0; mf < 4; ++mf)
#pragma unroll
  for (int t = 0; t < 3; ++t)
#pragma unroll
  for (int i = 0; i < 4; ++i){
    int l = l0 + mf*16 + g*4 + i;
    int j = j0 + wv*48 + t*16 + r;
    int which = j >> 8, h = (j >> 5) & 7, d = j & 31;
    int pair = n*8 + h;
    float v = acc[mf][t][i];
    if (which == 0)      qw[((size_t)pair*L_SEQ + l)*32 + d] = f2bf(v * QSCALE);
    else if (which == 1) kw[((size_t)pair*L_SEQ + l)*32 + d] = f2bf(v);
    else                 vtw[((size_t)pair*32 + d)*L_SEQ + l] = f2bf(v);
  }
}

// ---------------------------------------------------------------------------
// Flash attention, SOFTWARE-PIPELINED version of the round-5 green kernel.
// Per iter t: [ka(t), va(t-1) LDS reads] B1 [QK(t) MFMA] [PV+ls(t-1) MFMA from
// packed pu_prev] [exp2+pack(t) VALU overlaps MFMA drain] [stage t+1] B2.
// PV/QK chains are independent -> MFMA and VALU pipes overlap within a wave.
// pu_prev zero-init + V_lds[1] zeroed => t=0 dummy PV contributes exact zero.
// ---------------------------------------------------------------------------
__global__ __launch_bounds__(512,3) void attn_kernel(
    const short* __restrict__ qw, const short* __restrict__ kw,
    const short* __restrict__ vtw, float* __restrict__ out){
  __shared__ __align__(16) short K_lds[2][64][64];  // [buf][key][XOR-spread chunks]
  __shared__ __align__(16) short V_lds[2][32][64];
  const int KB = 64*64*2, VB = 32*64*2;

  int bid = blockIdx.x;
  int xcd = bid & 7, jj = bid >> 3;
  int pair = (jj >> 4)*8 + xcd;                     // 4 pairs per XCD
  int q0 = (jj & 15)*256;
  int n = pair >> 3, h = pair & 7;
  int tid = threadIdx.x, wv = tid >> 6, lane = tid & 63;
  int qc = lane & 31, hi = lane >> 5;

  const short* qb_ = qw + (size_t)pair*L_SEQ*32;
  const short* kptr = kw + (size_t)pair*L_SEQ*32 + (size_t)(tid>>3)*32 + (tid&7)*4;
  const short* vptr = vtw + (size_t)pair*32*L_SEQ + (size_t)(tid>>4)*L_SEQ + (tid&15)*4;

  bf16x8 qf0 = *(const bf16x8*)(qb_ + (size_t)(q0 + wv*32 + qc)*32 + hi*8);
  bf16x8 qf1 = *(const bf16x8*)(qb_ + (size_t)(q0 + wv*32 + qc)*32 + 16 + hi*8);

  int skey = tid >> 3, sdc = tid & 7;
  int svd  = tid >> 4, svc = tid & 15;
  char* kdst = (char*)&K_lds[0][skey][0] + (((sdc>>1) ^ (skey&7))*16) + (sdc&1)*8;
  char* vdst = (char*)&V_lds[0][svd][0] + (((svc>>1) ^ (svd&7))*16) + (svc&1)*8;

  int ka_off[2][2];
#pragma unroll
  for (int sub = 0; sub < 2; ++sub)
#pragma unroll
  for (int dh = 0; dh < 2; ++dh){
    int row = sub*32 + qc;
    ka_off[sub][dh] = row*128 + (((dh*2 + hi) ^ (row & 7))*16);
  }
  int va_off[4];
#pragma unroll
  for (int m = 0; m < 4; ++m) va_off[m] = qc*128 + (((2*m + hi) ^ (qc & 7))*16);

  const bf16x8 onesv = {0x3F80,0x3F80,0x3F80,0x3F80,0x3F80,0x3F80,0x3F80,0x3F80};

  f32x16 o = {}, ls = {};
  unsigned pu_prev[4][4];
#pragma unroll
  for (int m = 0; m < 4; ++m)
#pragma unroll
    for (int w = 0; w < 4; ++w) pu_prev[m][w] = 0u;

  { // prologue: stage tile 0 into buf 0; zero V_lds[1] (t=0 dummy PV reads it)
    int2 kv = *(const int2*)kptr;
    int2 vv = *(const int2*)vptr;
    *(int2*)kdst = kv;
    *(int2*)vdst = vv;
    if (tid < 256){
      int4 zz = {0,0,0,0};
      *(int4*)((char*)&V_lds[1][0][0] + tid*16) = zz;
    }
  }
  __syncthreads();

  for (int t = 0; t < 64; ++t){
    int buf = t & 1;
    const char* kB_ = (const char*)K_lds + buf*KB;
    const char* vB_ = (const char*)V_lds + (buf^1)*VB;   // tile t-1's V

    // --- LDS reads: K of tile t, V of tile t-1 (before B1: WAR hazard fence) ---
    bf16x8 ka00 = *(const bf16x8*)(kB_ + ka_off[0][0]);
    bf16x8 ka01 = *(const bf16x8*)(kB_ + ka_off[0][1]);
    bf16x8 ka10 = *(const bf16x8*)(kB_ + ka_off[1][0]);
    bf16x8 ka11 = *(const bf16x8*)(kB_ + ka_off[1][1]);
    bf16x8 va[4];
#pragma unroll
    for (int m = 0; m < 4; ++m) va[m] = *(const bf16x8*)(vB_ + va_off[m]);
    __syncthreads();                                     // B1

    // --- QK^T for tile t ---
    f32x16 z = {};
    __builtin_amdgcn_s_setprio(1);
    f32x16 s0 = __builtin_amdgcn_mfma_f32_32x32x16_bf16(ka00, qf0, z, 0,0,0);
    s0        = __builtin_amdgcn_mfma_f32_32x32x16_bf16(ka01, qf1, s0, 0,0,0);
    f32x16 s1 = __builtin_amdgcn_mfma_f32_32x32x16_bf16(ka10, qf0, z, 0,0,0);
    s1        = __builtin_amdgcn_mfma_f32_32x32x16_bf16(ka11, qf1, s1, 0,0,0);
    __builtin_amdgcn_s_setprio(0);

    // --- global prefetch for tile t+1 (issue early, write after compute) ---
    int2 kv, vv;
    bool pf = (t < 63);
    if (pf){
      kptr += 64*32; vptr += 64;
      kv = *(const int2*)kptr;
      vv = *(const int2*)vptr;
    }

    // --- PV + ls for tile t-1 (independent of QK(t): fills MFMA pipe) ---
#pragma unroll
    for (int m = 0; m < 4; ++m){
      union{ unsigned w[4]; bf16x8 v; } pu;
      pu.w[0] = pu_prev[m][0]; pu.w[1] = pu_prev[m][1];
      pu.w[2] = pu_prev[m][2]; pu.w[3] = pu_prev[m][3];
      o  = __builtin_amdgcn_mfma_f32_32x32x16_bf16(va[m], pu.v, o,  0,0,0);
      ls = __builtin_amdgcn_mfma_f32_32x32x16_bf16(onesv, pu.v, ls, 0,0,0);
    }

    // --- exp2 + pack tile t -> pu_prev (VALU; overlaps MFMA drain above) ---
#pragma unroll
    for (int i = 0; i < 16; ++i) s0[i] = __builtin_amdgcn_exp2f(s0[i]);
#pragma unroll
    for (int i = 0; i < 16; ++i) s1[i] = __builtin_amdgcn_exp2f(s1[i]);
#pragma unroll
    for (int m = 0; m < 4; ++m){
      int b = (m & 1)*8;
      unsigned g0a, g0b, g4a, g4b;
      if (m < 2){
        g0a = cvtpk(s0[b+0], s0[b+1]); g0b = cvtpk(s0[b+2], s0[b+3]);
        g4a = cvtpk(s0[b+4], s0[b+5]); g4b = cvtpk(s0[b+6], s0[b+7]);
      } else {
        g0a = cvtpk(s1[b+0], s1[b+1]); g0b = cvtpk(s1[b+2], s1[b+3]);
        g4a = cvtpk(s1[b+4], s1[b+5]); g4b = cvtpk(s1[b+6], s1[b+7]);
      }
      plswap(g0a, g4a);                        // -> word0, word2
      plswap(g0b, g4b);                        // -> word1, word3
      pu_prev[m][0] = g0a; pu_prev[m][1] = g0b;
      pu_prev[m][2] = g4a; pu_prev[m][3] = g4b;
    }

    // --- stage tile t+1 into buf^1 ---
    if (pf){
      *(int2*)(kdst + (buf^1)*KB) = kv;
      *(int2*)(vdst + (buf^1)*VB) = vv;
    }
    __syncthreads();                                     // B2
  }

  // --- epilogue: PV + ls for tile 63 (its V is in buf 1; no writes after) ---
  {
    const char* vB_ = (const char*)V_lds + 1*VB;
    bf16x8 va[4];
#pragma unroll
    for (int m = 0; m < 4; ++m) va[m] = *(const bf16x8*)(vB_ + va_off[m]);
#pragma unroll
    for (int m = 0; m < 4; ++m){
      union{ unsigned w[4]; bf16x8 v; } pu;
      pu.w[0] = pu_prev[m][0]; pu.w[1] = pu_prev[m][1];
      pu.w[2] = pu_prev[m][2]; pu.w[3] = pu_prev[m][3];
      o  = __builtin_amdgcn_mfma_f32_32x32x16_bf16(va[m], pu.v, o,  0,0,0);
      ls = __builtin_amdgcn_mfma_f32_32x32x16_bf16(onesv, pu.v, ls, 0,0,0);
    }
  }

  float rinv = 1.0f / ls[0];                   // all 16 regs identical
#pragma unroll
  for (int reg = 0; reg < 16; ++reg){
    int d = (reg & 3) + 8*(reg >> 2) + 4*hi;
    out[(size_t)(n*C_DIM + h*32 + d)*L_SEQ + q0 + wv*32 + qc] = o[reg]*rinv;
  }
}

// ---------------------------------------------------------------------------
extern "C" void kernel_launch(void* const* d_in, const int* in_sizes, int n_in,
                              void* d_out, int out_size, void* d_ws, size_t ws_size,
                              hipStream_t stream) {
  const float* x = (const float*)d_in[0];
  const float* W = (const float*)d_in[1];
  float* out = (float*)d_out;
  char* ws = (char*)d_ws;
  short* pe_t = (short*)ws;                              // 2 MB
  short* wT   = (short*)(ws + (size_t)2*1024*1024);      // 0.4 MB (1 MB slot)
  short* qw   = (short*)(ws + (size_t)3*1024*1024);      // 8 MB
  short* kw   = (short*)(ws + (size_t)11*1024*1024);     // 8 MB
  short* vtw  = (short*)(ws + (size_t)19*1024*1024);     // 8 MB

  tables_kernel<<<dim3(4864), 256, 0, stream>>>(W, pe_t, wT);
  qkv_gemm<<<dim3(256, 4), 256, 0, stream>>>(x, pe_t, wT, qw, kw, vtw);
  attn_kernel<<<dim3(512), 512, 0, stream>>>(qw, kw, vtw, out);
}

// Round 7
// 195.443 us; speedup vs baseline: 1.0975x; 1.0975x over previous
//
#include <hip/hip_runtime.h>
#include <hip/hip_bf16.h>

#define L_SEQ 4096
#define C_DIM 256
#define QKV_N 768

typedef short bf16x8 __attribute__((ext_vector_type(8)));
typedef float f32x4  __attribute__((ext_vector_type(4)));
typedef float f32x16 __attribute__((ext_vector_type(16)));

#if defined(__has_builtin)
#  if __has_builtin(__builtin_amdgcn_permlane32_swap)
#    define HAVE_PLSWAP 1
#  endif
#endif

__device__ inline short f2bf(float f){ union{__hip_bfloat16 h; short s;}u; u.h=__float2bfloat16(f); return u.s; }
__device__ inline float bf2f(short s){ union{unsigned u; float f;}x; x.u=((unsigned)(unsigned short)s)<<16; return x.f; }

__device__ inline unsigned cvtpk(float lo, float hi){
  unsigned r;
  asm("v_cvt_pk_bf16_f32 %0, %1, %2" : "=v"(r) : "v"(lo), "v"(hi));
  return r;
}

__device__ inline void plswap(unsigned &a, unsigned &b){
#ifdef HAVE_PLSWAP
  auto r = __builtin_amdgcn_permlane32_swap(a, b, false, false);
  a = r[0]; b = r[1];
#else
  unsigned ax = __shfl_xor((int)a, 32);
  unsigned bx = __shfl_xor((int)b, 32);
  bool hi = (threadIdx.x & 32) != 0;
  unsigned na = hi ? bx : a;
  unsigned nb = hi ? b : ax;
  a = na; b = nb;
#endif
}

// ---------------------------------------------------------------------------
// tables: pe_t[c][l] bf16 (blocks 0..4095)  |  wT[j][k] bf16 (blocks 4096..4863)
// (byte-identical to round-5 green version)
// ---------------------------------------------------------------------------
__global__ __launch_bounds__(256) void tables_kernel(
    const float* __restrict__ W, short* __restrict__ pe_t, short* __restrict__ wT){
  int bid = blockIdx.x;
  if (bid < 4096){
    int idx = bid*256 + threadIdx.x;           // c*4096 + l
    int c = idx >> 12, l = idx & 4095;
    int c2 = c & ~1;
    float inv = __expf(-(float)c2 * (9.210340371976184f/256.0f));   // 10000^(-c2/256)
    float rev = (float)l * inv * 0.15915494309189535f;              // revolutions
    float fr = rev - floorf(rev);
    float v = (c & 1) ? __builtin_amdgcn_cosf(fr) : __builtin_amdgcn_sinf(fr);
    pe_t[idx] = f2bf(v);
  } else {
    int idx = (bid - 4096)*256 + threadIdx.x;  // jj*256 + k
    int jj = idx >> 8, k = idx & 255;
    wT[idx] = f2bf(W[k*QKV_N + jj]);
  }
}

// ---------------------------------------------------------------------------
// qkv GEMM (byte-identical to round-5 green version): BM=64, BN=192, 4 waves,
// A staged once, B dbuf. 64.5KB LDS -> 2 blocks/CU, grid (256,4).
// ---------------------------------------------------------------------------
__global__ __launch_bounds__(256) void qkv_gemm(
    const float* __restrict__ x, const short* __restrict__ pe_t, const short* __restrict__ wT,
    short* __restrict__ qw, short* __restrict__ kw, short* __restrict__ vtw){
  __shared__ __align__(16) short A_lds[64][264];     // [l][c] pad (528B rows) 33.8KB
  __shared__ __align__(16) short B_lds[2][192][40];  // [buf][j][k] pad (80B rows) 30.7KB
  int m0 = blockIdx.x * 64;
  int n = m0 >> 12, l0 = m0 & 4095;
  int j0 = blockIdx.y * 192;
  int tid = threadIdx.x;

  {  // ---- stage A = bf16(x^T + pe), 64 x 256, once; thread = one c-column ----
    int c = tid;
    const float* xp = x + ((size_t)n*C_DIM + c)*L_SEQ + l0;
    const short* pp = pe_t + (size_t)c*L_SEQ + l0;
    float xv[64];
#pragma unroll
    for (int q = 0; q < 16; ++q) *(float4*)&xv[q*4] = ((const float4*)xp)[q];
    short pv[64];
#pragma unroll
    for (int q = 0; q < 8; ++q) *(bf16x8*)&pv[q*8] = ((const bf16x8*)pp)[q];
#pragma unroll
    for (int i = 0; i < 64; ++i) A_lds[i][c] = f2bf(xv[i] + bf2f(pv[i]));
  }
  {  // ---- stage B slice 0 (192 x 32 shorts = 768 x 16B chunks, 256 thr x 3) ----
#pragma unroll
    for (int s = 0; s < 3; ++s){
      int chunk = tid + s*256;
      int j = chunk >> 2, kc = chunk & 3;
      *(bf16x8*)&B_lds[0][j][kc*8] = *(const bf16x8*)(wT + (size_t)(j0 + j)*256 + kc*8);
    }
  }
  __syncthreads();

  int wv = tid >> 6, lane = tid & 63, r = lane & 15, g = lane >> 4;
  f32x4 acc[4][3] = {};

  for (int ks = 0; ks < 8; ++ks){
    int buf = ks & 1;
    bf16x8 pre[3];
    if (ks < 7){                                 // issue next-slice loads early
#pragma unroll
      for (int s = 0; s < 3; ++s){
        int chunk = tid + s*256;
        int j = chunk >> 2, kc = chunk & 3;
        pre[s] = *(const bf16x8*)(wT + (size_t)(j0 + j)*256 + (ks+1)*32 + kc*8);
      }
    }
    bf16x8 a[4];
#pragma unroll
    for (int mf = 0; mf < 4; ++mf)
      a[mf] = *(const bf16x8*)&A_lds[mf*16 + r][ks*32 + g*8];
#pragma unroll
    for (int t = 0; t < 3; ++t){
      bf16x8 b = *(const bf16x8*)&B_lds[buf][wv*48 + t*16 + r][g*8];
#pragma unroll
      for (int mf = 0; mf < 4; ++mf)
        acc[mf][t] = __builtin_amdgcn_mfma_f32_16x16x32_bf16(a[mf], b, acc[mf][t], 0,0,0);
    }
    if (ks < 7){                                 // write NEXT slice to other buffer
#pragma unroll
      for (int s = 0; s < 3; ++s){
        int chunk = tid + s*256;
        int j = chunk >> 2, kc = chunk & 3;
        *(bf16x8*)&B_lds[buf^1][j][kc*8] = pre[s];
      }
    }
    __syncthreads();
  }

  const float QSCALE = 0.17677669529663687f * 1.4426950408889634f;  // 1/sqrt(32) * log2e
#pragma unroll
  for (int mf = 0; mf < 4; ++mf)
#pragma unroll
  for (int t = 0; t < 3; ++t)
#pragma unroll
  for (int i = 0; i < 4; ++i){
    int l = l0 + mf*16 + g*4 + i;
    int j = j0 + wv*48 + t*16 + r;
    int which = j >> 8, h = (j >> 5) & 7, d = j & 31;
    int pair = n*8 + h;
    float v = acc[mf][t][i];
    if (which == 0)      qw[((size_t)pair*L_SEQ + l)*32 + d] = f2bf(v * QSCALE);
    else if (which == 1) kw[((size_t)pair*L_SEQ + l)*32 + d] = f2bf(v);
    else                 vtw[((size_t)pair*32 + d)*L_SEQ + l] = f2bf(v);
  }
}

// ---------------------------------------------------------------------------
// Flash attention: R5-green inner structure (1 barrier/tile, serial
// QK->exp->pack->PV per wave), but 4-WAVE blocks (256 thr, 128 q-rows),
// grid 1024 -> 4 independent barrier groups per CU for cross-block
// MFMA/VALU phase overlap. Staging slot math identical to R5 (s-loop x2).
// ---------------------------------------------------------------------------
__global__ __launch_bounds__(256,4) void attn_kernel(
    const short* __restrict__ qw, const short* __restrict__ kw,
    const short* __restrict__ vtw, float* __restrict__ out){
  __shared__ __align__(16) short K_lds[2][64][64];  // [buf][key][XOR-spread chunks] 16KB
  __shared__ __align__(16) short V_lds[2][32][64];  // 8KB
  const int KB = 64*64*2, VB = 32*64*2;

  int bid = blockIdx.x;
  int xcd = bid & 7, jj = bid >> 3;                 // 128 jj per XCD-class
  int pair = (jj >> 5)*8 + xcd;                     // 32 q-blocks of one pair per XCD
  int q0 = (jj & 31)*128;
  int n = pair >> 3, h = pair & 7;
  int tid = threadIdx.x, wv = tid >> 6, lane = tid & 63;
  int qc = lane & 31, hi = lane >> 5;

  const short* qb_ = qw + (size_t)pair*L_SEQ*32;
  // staging addresses for s in {0,1}: idx = tid + s*256, R5-identical slot math
  const short* kptr[2]; const short* vptr[2];
  char* kdst[2]; char* vdst[2];
#pragma unroll
  for (int s = 0; s < 2; ++s){
    int idx = tid + s*256;
    int skey = idx >> 3, sdc = idx & 7;
    int svd  = idx >> 4, svc = idx & 15;
    kptr[s] = kw + (size_t)pair*L_SEQ*32 + (size_t)skey*32 + sdc*4;
    vptr[s] = vtw + (size_t)pair*32*L_SEQ + (size_t)svd*L_SEQ + svc*4;
    kdst[s] = (char*)&K_lds[0][skey][0] + (((sdc>>1) ^ (skey&7))*16) + (sdc&1)*8;
    vdst[s] = (char*)&V_lds[0][svd][0] + (((svc>>1) ^ (svd&7))*16) + (svc&1)*8;
  }

  bf16x8 qf0 = *(const bf16x8*)(qb_ + (size_t)(q0 + wv*32 + qc)*32 + hi*8);
  bf16x8 qf1 = *(const bf16x8*)(qb_ + (size_t)(q0 + wv*32 + qc)*32 + 16 + hi*8);

  int ka_off[2][2];
#pragma unroll
  for (int sub = 0; sub < 2; ++sub)
#pragma unroll
  for (int dh = 0; dh < 2; ++dh){
    int row = sub*32 + qc;
    ka_off[sub][dh] = row*128 + (((dh*2 + hi) ^ (row & 7))*16);
  }
  int va_off[4];
#pragma unroll
  for (int m = 0; m < 4; ++m) va_off[m] = qc*128 + (((2*m + hi) ^ (qc & 7))*16);

  const bf16x8 onesv = {0x3F80,0x3F80,0x3F80,0x3F80,0x3F80,0x3F80,0x3F80,0x3F80};

  f32x16 o = {}, ls = {};

  { // prologue: stage tile 0 into buf 0
#pragma unroll
    for (int s = 0; s < 2; ++s){
      *(int2*)kdst[s] = *(const int2*)kptr[s];
      *(int2*)vdst[s] = *(const int2*)vptr[s];
    }
  }
  __syncthreads();

  for (int t = 0; t < 64; ++t){
    int buf = t & 1;
    const char* kB_ = (const char*)K_lds + buf*KB;
    const char* vB_ = (const char*)V_lds + buf*VB;

    bf16x8 ka00 = *(const bf16x8*)(kB_ + ka_off[0][0]);
    bf16x8 ka01 = *(const bf16x8*)(kB_ + ka_off[0][1]);
    bf16x8 ka10 = *(const bf16x8*)(kB_ + ka_off[1][0]);
    bf16x8 ka11 = *(const bf16x8*)(kB_ + ka_off[1][1]);

    f32x16 z = {};
    __builtin_amdgcn_s_setprio(1);
    f32x16 s0 = __builtin_amdgcn_mfma_f32_32x32x16_bf16(ka00, qf0, z, 0,0,0);
    s0        = __builtin_amdgcn_mfma_f32_32x32x16_bf16(ka01, qf1, s0, 0,0,0);
    f32x16 s1 = __builtin_amdgcn_mfma_f32_32x32x16_bf16(ka10, qf0, z, 0,0,0);
    s1        = __builtin_amdgcn_mfma_f32_32x32x16_bf16(ka11, qf1, s1, 0,0,0);
    __builtin_amdgcn_s_setprio(0);

    int2 kv[2], vv[2];
    bool pf = (t < 63);
    if (pf){
#pragma unroll
      for (int s = 0; s < 2; ++s){
        kptr[s] += 64*32; vptr[s] += 64;
        kv[s] = *(const int2*)kptr[s];           // issue early: hides under exp/PV
        vv[s] = *(const int2*)vptr[s];
      }
    }

#pragma unroll
    for (int i = 0; i < 16; ++i) s0[i] = __builtin_amdgcn_exp2f(s0[i]);
#pragma unroll
    for (int i = 0; i < 16; ++i) s1[i] = __builtin_amdgcn_exp2f(s1[i]);

#pragma unroll
    for (int m = 0; m < 4; ++m){
      int b = (m & 1)*8;
      unsigned g0a, g0b, g4a, g4b;
      if (m < 2){
        g0a = cvtpk(s0[b+0], s0[b+1]); g0b = cvtpk(s0[b+2], s0[b+3]);
        g4a = cvtpk(s0[b+4], s0[b+5]); g4b = cvtpk(s0[b+6], s0[b+7]);
      } else {
        g0a = cvtpk(s1[b+0], s1[b+1]); g0b = cvtpk(s1[b+2], s1[b+3]);
        g4a = cvtpk(s1[b+4], s1[b+5]); g4b = cvtpk(s1[b+6], s1[b+7]);
      }
      plswap(g0a, g4a);                        // -> word0, word2
      plswap(g0b, g4b);                        // -> word1, word3
      union{ unsigned w[4]; bf16x8 v; } pu;
      pu.w[0] = g0a; pu.w[1] = g0b; pu.w[2] = g4a; pu.w[3] = g4b;
      bf16x8 va = *(const bf16x8*)(vB_ + va_off[m]);
      o  = __builtin_amdgcn_mfma_f32_32x32x16_bf16(va,    pu.v, o,  0,0,0);
      ls = __builtin_amdgcn_mfma_f32_32x32x16_bf16(onesv, pu.v, ls, 0,0,0);
    }

    if (pf){
#pragma unroll
      for (int s = 0; s < 2; ++s){
        *(int2*)(kdst[s] + (buf^1)*KB) = kv[s];
        *(int2*)(vdst[s] + (buf^1)*VB) = vv[s];
      }
    }
    __syncthreads();
  }

  float rinv = 1.0f / ls[0];                   // all 16 regs identical
#pragma unroll
  for (int reg = 0; reg < 16; ++reg){
    int d = (reg & 3) + 8*(reg >> 2) + 4*hi;
    out[(size_t)(n*C_DIM + h*32 + d)*L_SEQ + q0 + wv*32 + qc] = o[reg]*rinv;
  }
}

// ---------------------------------------------------------------------------
extern "C" void kernel_launch(void* const* d_in, const int* in_sizes, int n_in,
                              void* d_out, int out_size, void* d_ws, size_t ws_size,
                              hipStream_t stream) {
  const float* x = (const float*)d_in[0];
  const float* W = (const float*)d_in[1];
  float* out = (float*)d_out;
  char* ws = (char*)d_ws;
  short* pe_t = (short*)ws;                              // 2 MB
  short* wT   = (short*)(ws + (size_t)2*1024*1024);      // 0.4 MB (1 MB slot)
  short* qw   = (short*)(ws + (size_t)3*1024*1024);      // 8 MB
  short* kw   = (short*)(ws + (size_t)11*1024*1024);     // 8 MB
  short* vtw  = (short*)(ws + (size_t)19*1024*1024);     // 8 MB

  tables_kernel<<<dim3(4864), 256, 0, stream>>>(W, pe_t, wT);
  qkv_gemm<<<dim3(256, 4), 256, 0, stream>>>(x, pe_t, wT, qw, kw, vtw);
  attn_kernel<<<dim3(1024), 256, 0, stream>>>(qw, kw, vtw, out);
}

// Round 8
// 185.479 us; speedup vs baseline: 1.1564x; 1.0537x over previous
//
#include <hip/hip_runtime.h>
#include <hip/hip_bf16.h>

#define L_SEQ 4096
#define C_DIM 256
#define QKV_N 768

typedef short bf16x8 __attribute__((ext_vector_type(8)));
typedef float f32x4  __attribute__((ext_vector_type(4)));
typedef float f32x16 __attribute__((ext_vector_type(16)));

#if defined(__has_builtin)
#  if __has_builtin(__builtin_amdgcn_permlane32_swap)
#    define HAVE_PLSWAP 1
#  endif
#endif

__device__ inline short f2bf(float f){ union{__hip_bfloat16 h; short s;}u; u.h=__float2bfloat16(f); return u.s; }
__device__ inline float bf2f(short s){ union{unsigned u; float f;}x; x.u=((unsigned)(unsigned short)s)<<16; return x.f; }

__device__ inline unsigned cvtpk(float lo, float hi){
  unsigned r;
  asm("v_cvt_pk_bf16_f32 %0, %1, %2" : "=v"(r) : "v"(lo), "v"(hi));
  return r;
}

__device__ inline void plswap(unsigned &a, unsigned &b){
#ifdef HAVE_PLSWAP
  auto r = __builtin_amdgcn_permlane32_swap(a, b, false, false);
  a = r[0]; b = r[1];
#else
  unsigned ax = __shfl_xor((int)a, 32);
  unsigned bx = __shfl_xor((int)b, 32);
  bool hi = (threadIdx.x & 32) != 0;
  unsigned na = hi ? bx : a;
  unsigned nb = hi ? b : ax;
  a = na; b = nb;
#endif
}

// ---------------------------------------------------------------------------
// tables: pe_t[c][l] bf16 (blocks 0..4095)  |  wT[j][k] bf16 (blocks 4096..4863)
// (byte-identical to round-5 green version)
// ---------------------------------------------------------------------------
__global__ __launch_bounds__(256) void tables_kernel(
    const float* __restrict__ W, short* __restrict__ pe_t, short* __restrict__ wT){
  int bid = blockIdx.x;
  if (bid < 4096){
    int idx = bid*256 + threadIdx.x;           // c*4096 + l
    int c = idx >> 12, l = idx & 4095;
    int c2 = c & ~1;
    float inv = __expf(-(float)c2 * (9.210340371976184f/256.0f));   // 10000^(-c2/256)
    float rev = (float)l * inv * 0.15915494309189535f;              // revolutions
    float fr = rev - floorf(rev);
    float v = (c & 1) ? __builtin_amdgcn_cosf(fr) : __builtin_amdgcn_sinf(fr);
    pe_t[idx] = f2bf(v);
  } else {
    int idx = (bid - 4096)*256 + threadIdx.x;  // jj*256 + k
    int jj = idx >> 8, k = idx & 255;
    wT[idx] = f2bf(W[k*QKV_N + jj]);
  }
}

// ---------------------------------------------------------------------------
// qkv GEMM (byte-identical to round-5 green version): BM=64, BN=192, 4 waves,
// A staged once, B dbuf. 64.5KB LDS -> 2 blocks/CU, grid (256,4).
// ---------------------------------------------------------------------------
__global__ __launch_bounds__(256) void qkv_gemm(
    const float* __restrict__ x, const short* __restrict__ pe_t, const short* __restrict__ wT,
    short* __restrict__ qw, short* __restrict__ kw, short* __restrict__ vtw){
  __shared__ __align__(16) short A_lds[64][264];     // [l][c] pad (528B rows) 33.8KB
  __shared__ __align__(16) short B_lds[2][192][40];  // [buf][j][k] pad (80B rows) 30.7KB
  int m0 = blockIdx.x * 64;
  int n = m0 >> 12, l0 = m0 & 4095;
  int j0 = blockIdx.y * 192;
  int tid = threadIdx.x;

  {  // ---- stage A = bf16(x^T + pe), 64 x 256, once; thread = one c-column ----
    int c = tid;
    const float* xp = x + ((size_t)n*C_DIM + c)*L_SEQ + l0;
    const short* pp = pe_t + (size_t)c*L_SEQ + l0;
    float xv[64];
#pragma unroll
    for (int q = 0; q < 16; ++q) *(float4*)&xv[q*4] = ((const float4*)xp)[q];
    short pv[64];
#pragma unroll
    for (int q = 0; q < 8; ++q) *(bf16x8*)&pv[q*8] = ((const bf16x8*)pp)[q];
#pragma unroll
    for (int i = 0; i < 64; ++i) A_lds[i][c] = f2bf(xv[i] + bf2f(pv[i]));
  }
  {  // ---- stage B slice 0 (192 x 32 shorts = 768 x 16B chunks, 256 thr x 3) ----
#pragma unroll
    for (int s = 0; s < 3; ++s){
      int chunk = tid + s*256;
      int j = chunk >> 2, kc = chunk & 3;
      *(bf16x8*)&B_lds[0][j][kc*8] = *(const bf16x8*)(wT + (size_t)(j0 + j)*256 + kc*8);
    }
  }
  __syncthreads();

  int wv = tid >> 6, lane = tid & 63, r = lane & 15, g = lane >> 4;
  f32x4 acc[4][3] = {};

  for (int ks = 0; ks < 8; ++ks){
    int buf = ks & 1;
    bf16x8 pre[3];
    if (ks < 7){                                 // issue next-slice loads early
#pragma unroll
      for (int s = 0; s < 3; ++s){
        int chunk = tid + s*256;
        int j = chunk >> 2, kc = chunk & 3;
        pre[s] = *(const bf16x8*)(wT + (size_t)(j0 + j)*256 + (ks+1)*32 + kc*8);
      }
    }
    bf16x8 a[4];
#pragma unroll
    for (int mf = 0; mf < 4; ++mf)
      a[mf] = *(const bf16x8*)&A_lds[mf*16 + r][ks*32 + g*8];
#pragma unroll
    for (int t = 0; t < 3; ++t){
      bf16x8 b = *(const bf16x8*)&B_lds[buf][wv*48 + t*16 + r][g*8];
#pragma unroll
      for (int mf = 0; mf < 4; ++mf)
        acc[mf][t] = __builtin_amdgcn_mfma_f32_16x16x32_bf16(a[mf], b, acc[mf][t], 0,0,0);
    }
    if (ks < 7){                                 // write NEXT slice to other buffer
#pragma unroll
      for (int s = 0; s < 3; ++s){
        int chunk = tid + s*256;
        int j = chunk >> 2, kc = chunk & 3;
        *(bf16x8*)&B_lds[buf^1][j][kc*8] = pre[s];
      }
    }
    __syncthreads();
  }

  const float QSCALE = 0.17677669529663687f * 1.4426950408889634f;  // 1/sqrt(32) * log2e
#pragma unroll
  for (int mf = 0; mf < 4; ++mf)
#pragma unroll
  for (int t = 0; t < 3; ++t)
#pragma unroll
  for (int i = 0; i < 4; ++i){
    int l = l0 + mf*16 + g*4 + i;
    int j = j0 + wv*48 + t*16 + r;
    int which = j >> 8, h = (j >> 5) & 7, d = j & 31;
    int pair = n*8 + h;
    float v = acc[mf][t][i];
    if (which == 0)      qw[((size_t)pair*L_SEQ + l)*32 + d] = f2bf(v * QSCALE);
    else if (which == 1) kw[((size_t)pair*L_SEQ + l)*32 + d] = f2bf(v);
    else                 vtw[((size_t)pair*32 + d)*L_SEQ + l] = f2bf(v);
  }
}

// ---------------------------------------------------------------------------
// Flash attention: 64 q-rows PER WAVE (two 32-q groups A/B sharing all K/V
// fragments, staging, and loop overhead). 4-wave blocks (256 q/block),
// grid 512 (2 blocks/CU). Inner structure, staging slot math, fragment
// offsets identical to the round-7 green kernel; only q-side duplicated.
// ---------------------------------------------------------------------------
__global__ __launch_bounds__(256,2) void attn_kernel(
    const short* __restrict__ qw, const short* __restrict__ kw,
    const short* __restrict__ vtw, float* __restrict__ out){
  __shared__ __align__(16) short K_lds[2][64][64];  // [buf][key][XOR-spread chunks] 16KB
  __shared__ __align__(16) short V_lds[2][32][64];  // 8KB
  const int KB = 64*64*2, VB = 32*64*2;

  int bid = blockIdx.x;
  int xcd = bid & 7, jj = bid >> 3;                 // 64 jj per XCD-class
  int pair = (jj >> 4)*8 + xcd;                     // 4 pairs per XCD
  int q0 = (jj & 15)*256;
  int n = pair >> 3, h = pair & 7;
  int tid = threadIdx.x, wv = tid >> 6, lane = tid & 63;
  int qc = lane & 31, hi = lane >> 5;

  const short* qb_ = qw + (size_t)pair*L_SEQ*32;
  // staging addresses for s in {0,1}: idx = tid + s*256 (R7-identical slot math)
  const short* kptr[2]; const short* vptr[2];
  char* kdst[2]; char* vdst[2];
#pragma unroll
  for (int s = 0; s < 2; ++s){
    int idx = tid + s*256;
    int skey = idx >> 3, sdc = idx & 7;
    int svd  = idx >> 4, svc = idx & 15;
    kptr[s] = kw + (size_t)pair*L_SEQ*32 + (size_t)skey*32 + sdc*4;
    vptr[s] = vtw + (size_t)pair*32*L_SEQ + (size_t)svd*L_SEQ + svc*4;
    kdst[s] = (char*)&K_lds[0][skey][0] + (((sdc>>1) ^ (skey&7))*16) + (sdc&1)*8;
    vdst[s] = (char*)&V_lds[0][svd][0] + (((svc>>1) ^ (svd&7))*16) + (svc&1)*8;
  }

  // two q-groups per wave: rows q0 + wv*64 + {0,32} + qc
  const short* qpA = qb_ + (size_t)(q0 + wv*64 +  0 + qc)*32;
  const short* qpB = qb_ + (size_t)(q0 + wv*64 + 32 + qc)*32;
  bf16x8 qfA0 = *(const bf16x8*)(qpA + hi*8);
  bf16x8 qfA1 = *(const bf16x8*)(qpA + 16 + hi*8);
  bf16x8 qfB0 = *(const bf16x8*)(qpB + hi*8);
  bf16x8 qfB1 = *(const bf16x8*)(qpB + 16 + hi*8);

  int ka_off[2][2];
#pragma unroll
  for (int sub = 0; sub < 2; ++sub)
#pragma unroll
  for (int dh = 0; dh < 2; ++dh){
    int row = sub*32 + qc;
    ka_off[sub][dh] = row*128 + (((dh*2 + hi) ^ (row & 7))*16);
  }
  int va_off[4];
#pragma unroll
  for (int m = 0; m < 4; ++m) va_off[m] = qc*128 + (((2*m + hi) ^ (qc & 7))*16);

  const bf16x8 onesv = {0x3F80,0x3F80,0x3F80,0x3F80,0x3F80,0x3F80,0x3F80,0x3F80};

  f32x16 oA = {}, oB = {}, lsA = {}, lsB = {};

  { // prologue: stage tile 0 into buf 0
#pragma unroll
    for (int s = 0; s < 2; ++s){
      *(int2*)kdst[s] = *(const int2*)kptr[s];
      *(int2*)vdst[s] = *(const int2*)vptr[s];
    }
  }
  __syncthreads();

  for (int t = 0; t < 64; ++t){
    int buf = t & 1;
    const char* kB_ = (const char*)K_lds + buf*KB;
    const char* vB_ = (const char*)V_lds + buf*VB;

    bf16x8 ka00 = *(const bf16x8*)(kB_ + ka_off[0][0]);
    bf16x8 ka01 = *(const bf16x8*)(kB_ + ka_off[0][1]);
    bf16x8 ka10 = *(const bf16x8*)(kB_ + ka_off[1][0]);
    bf16x8 ka11 = *(const bf16x8*)(kB_ + ka_off[1][1]);

    f32x16 z = {};
    __builtin_amdgcn_s_setprio(1);
    f32x16 sA0 = __builtin_amdgcn_mfma_f32_32x32x16_bf16(ka00, qfA0, z,   0,0,0);
    sA0        = __builtin_amdgcn_mfma_f32_32x32x16_bf16(ka01, qfA1, sA0, 0,0,0);
    f32x16 sA1 = __builtin_amdgcn_mfma_f32_32x32x16_bf16(ka10, qfA0, z,   0,0,0);
    sA1        = __builtin_amdgcn_mfma_f32_32x32x16_bf16(ka11, qfA1, sA1, 0,0,0);
    f32x16 sB0 = __builtin_amdgcn_mfma_f32_32x32x16_bf16(ka00, qfB0, z,   0,0,0);
    sB0        = __builtin_amdgcn_mfma_f32_32x32x16_bf16(ka01, qfB1, sB0, 0,0,0);
    f32x16 sB1 = __builtin_amdgcn_mfma_f32_32x32x16_bf16(ka10, qfB0, z,   0,0,0);
    sB1        = __builtin_amdgcn_mfma_f32_32x32x16_bf16(ka11, qfB1, sB1, 0,0,0);
    __builtin_amdgcn_s_setprio(0);

    int2 kv[2], vv[2];
    bool pf = (t < 63);
    if (pf){
#pragma unroll
      for (int s = 0; s < 2; ++s){
        kptr[s] += 64*32; vptr[s] += 64;
        kv[s] = *(const int2*)kptr[s];           // issue early: hides under exp/PV
        vv[s] = *(const int2*)vptr[s];
      }
    }

#pragma unroll
    for (int i = 0; i < 16; ++i) sA0[i] = __builtin_amdgcn_exp2f(sA0[i]);
#pragma unroll
    for (int i = 0; i < 16; ++i) sA1[i] = __builtin_amdgcn_exp2f(sA1[i]);
#pragma unroll
    for (int i = 0; i < 16; ++i) sB0[i] = __builtin_amdgcn_exp2f(sB0[i]);
#pragma unroll
    for (int i = 0; i < 16; ++i) sB1[i] = __builtin_amdgcn_exp2f(sB1[i]);

#pragma unroll
    for (int m = 0; m < 4; ++m){
      int b = (m & 1)*8;
      bf16x8 va = *(const bf16x8*)(vB_ + va_off[m]);   // shared by both q-groups
      // group A
      {
        unsigned g0a, g0b, g4a, g4b;
        if (m < 2){
          g0a = cvtpk(sA0[b+0], sA0[b+1]); g0b = cvtpk(sA0[b+2], sA0[b+3]);
          g4a = cvtpk(sA0[b+4], sA0[b+5]); g4b = cvtpk(sA0[b+6], sA0[b+7]);
        } else {
          g0a = cvtpk(sA1[b+0], sA1[b+1]); g0b = cvtpk(sA1[b+2], sA1[b+3]);
          g4a = cvtpk(sA1[b+4], sA1[b+5]); g4b = cvtpk(sA1[b+6], sA1[b+7]);
        }
        plswap(g0a, g4a);
        plswap(g0b, g4b);
        union{ unsigned w[4]; bf16x8 v; } pu;
        pu.w[0] = g0a; pu.w[1] = g0b; pu.w[2] = g4a; pu.w[3] = g4b;
        oA  = __builtin_amdgcn_mfma_f32_32x32x16_bf16(va,    pu.v, oA,  0,0,0);
        lsA = __builtin_amdgcn_mfma_f32_32x32x16_bf16(onesv, pu.v, lsA, 0,0,0);
      }
      // group B
      {
        unsigned g0a, g0b, g4a, g4b;
        if (m < 2){
          g0a = cvtpk(sB0[b+0], sB0[b+1]); g0b = cvtpk(sB0[b+2], sB0[b+3]);
          g4a = cvtpk(sB0[b+4], sB0[b+5]); g4b = cvtpk(sB0[b+6], sB0[b+7]);
        } else {
          g0a = cvtpk(sB1[b+0], sB1[b+1]); g0b = cvtpk(sB1[b+2], sB1[b+3]);
          g4a = cvtpk(sB1[b+4], sB1[b+5]); g4b = cvtpk(sB1[b+6], sB1[b+7]);
        }
        plswap(g0a, g4a);
        plswap(g0b, g4b);
        union{ unsigned w[4]; bf16x8 v; } pu;
        pu.w[0] = g0a; pu.w[1] = g0b; pu.w[2] = g4a; pu.w[3] = g4b;
        oB  = __builtin_amdgcn_mfma_f32_32x32x16_bf16(va,    pu.v, oB,  0,0,0);
        lsB = __builtin_amdgcn_mfma_f32_32x32x16_bf16(onesv, pu.v, lsB, 0,0,0);
      }
    }

    if (pf){
#pragma unroll
      for (int s = 0; s < 2; ++s){
        *(int2*)(kdst[s] + (buf^1)*KB) = kv[s];
        *(int2*)(vdst[s] + (buf^1)*VB) = vv[s];
      }
    }
    __syncthreads();
  }

  float rinvA = 1.0f / lsA[0];                 // all 16 regs identical
  float rinvB = 1.0f / lsB[0];
#pragma unroll
  for (int reg = 0; reg < 16; ++reg){
    int d = (reg & 3) + 8*(reg >> 2) + 4*hi;
    size_t base = (size_t)(n*C_DIM + h*32 + d)*L_SEQ + q0 + wv*64 + qc;
    out[base]      = oA[reg]*rinvA;
    out[base + 32] = oB[reg]*rinvB;
  }
}

// ---------------------------------------------------------------------------
extern "C" void kernel_launch(void* const* d_in, const int* in_sizes, int n_in,
                              void* d_out, int out_size, void* d_ws, size_t ws_size,
                              hipStream_t stream) {
  const float* x = (const float*)d_in[0];
  const float* W = (const float*)d_in[1];
  float* out = (float*)d_out;
  char* ws = (char*)d_ws;
  short* pe_t = (short*)ws;                              // 2 MB
  short* wT   = (short*)(ws + (size_t)2*1024*1024);      // 0.4 MB (1 MB slot)
  short* qw   = (short*)(ws + (size_t)3*1024*1024);      // 8 MB
  short* kw   = (short*)(ws + (size_t)11*1024*1024);     // 8 MB
  short* vtw  = (short*)(ws + (size_t)19*1024*1024);     // 8 MB

  tables_kernel<<<dim3(4864), 256, 0, stream>>>(W, pe_t, wT);
  qkv_gemm<<<dim3(256, 4), 256, 0, stream>>>(x, pe_t, wT, qw, kw, vtw);
  attn_kernel<<<dim3(512), 256, 0, stream>>>(qw, kw, vtw, out);
}